// Round 11
// baseline (109.172 us; speedup 1.0000x reference)
//
#include <hip/hip_runtime.h>

// CRF loss on MI355X — R11 redesign.
//   R1-R10 post-mortem: matrix-chunk mode's VALU volume (16x16 matrix per
//   chunk = 16x the vector recursion's arithmetic) was the invariant ~70us
//   wall (VALUBusy 53% == real instruction count, all scheduling theories
//   exonerated). R11: batched-vector chain — 16 b's = 16 columns of ONE
//   MFMA B operand; A = E constant; v'[.][b'] = g ⊙ (E·v). 131K MFMAs
//   total (16x fewer). 128 blocks; warp3 = consumer (serial 1024-step
//   chain), warps 0-2 = producers staging g=exp(sigmoid(h)) into a
//   double-buffered 32-step LDS window (all trans-ops offloaded).
//   Per-column freeze (t >= len) via cndmask; per-window 2^-eb renorm;
//   E scaled 2^-4 per active step, corrected by 4*ln2*len at the end.
//   Z finished in-wave (phase2 eliminated).
// ws layout: [0,8KB) len (f32/b), [8KB,16KB) S (f32/b).

typedef unsigned int u32;
typedef float f32x4 __attribute__((ext_vector_type(4)));
typedef short s16x4 __attribute__((ext_vector_type(4)));
typedef unsigned int u32x2 __attribute__((ext_vector_type(2)));

#define LOG2E 1.4426950408889634f
#define LN2   0.6931471805599453f
#define Bsz   2048
#define Lsz   1024
#define BT    32768   /* Bsz*16 floats per timestep */
#define RS    132     /* LDS row stride in u32 (528B) */

#if __has_builtin(__builtin_amdgcn_exp2f)
__device__ __forceinline__ float exp2x(float x){ return __builtin_amdgcn_exp2f(x); }
#else
__device__ __forceinline__ float exp2x(float x){ return exp2f(x); }
#endif
#if __has_builtin(__builtin_amdgcn_logf)
__device__ __forceinline__ float log2x(float x){ return __builtin_amdgcn_logf(x); }
#else
__device__ __forceinline__ float log2x(float x){ return log2f(x); }
#endif
#if __has_builtin(__builtin_amdgcn_rcpf)
__device__ __forceinline__ float rcpx(float x){ return __builtin_amdgcn_rcpf(x); }
#else
__device__ __forceinline__ float rcpx(float x){ return 1.0f/x; }
#endif

__device__ __forceinline__ u32 cvtpk_bf16(float lo, float hi){
  u32 r;
  asm("v_cvt_pk_bf16_f32 %0, %1, %2" : "=v"(r) : "v"(lo), "v"(hi));
  return r;
}

// R1-proven inline-asm MFMA with conservative hazard padding.
__device__ __forceinline__ f32x4 mfma16(s16x4 a, s16x4 b, f32x4 c){
  f32x4 d;
  asm volatile("s_nop 1\n\t"
      "v_mfma_f32_16x16x16_bf16 %0, %1, %2, %3\n\t"
      "s_nop 7\n\t"
      "s_nop 7"
      : "=&v"(d) : "v"(a), "v"(b), "v"(c));
  return d;
}

__global__ __launch_bounds__(256) void k_zero(float* lenw, float* Sw, float* out){
  int i = blockIdx.x*256 + threadIdx.x;
  if (i < Bsz) lenw[i] = 0.f;
  else if (i < 2*Bsz) Sw[i - Bsz] = 0.f;
  if (i == 0) out[0] = 0.f;
}

// lengths[b] = sum_t mask[t,b]; S[b] partial = sum_t trans[y0[t+1],y0[t]]*mask[t]
__global__ __launch_bounds__(256) void k_score(const int* __restrict__ y0,
    const float* __restrict__ mask, const float* __restrict__ trans,
    float* __restrict__ lenw, float* __restrict__ Sw){
  __shared__ float Tt[256];
  Tt[threadIdx.x] = trans[threadIdx.x];
  __syncthreads();
  int gid = blockIdx.x*256 + threadIdx.x;   // 65536 threads: b fast, tc slow
  int b  = gid & (Bsz-1);
  int tc = gid >> 11;                        // 0..31, 32 t's each
  int t0 = tc * 32;
  float lacc = 0.f, sacc = 0.f;
  int yc = y0[t0*Bsz + b];
  #pragma unroll 4
  for (int t = t0; t < t0+32; ++t) {
    float m = mask[t*Bsz + b];
    int yn = y0[(t+1)*Bsz + b];
    lacc += m;
    if (t <= Lsz-2) sacc += m * Tt[yn*16 + yc];
    yc = yn;
  }
  atomicAdd(&lenw[b], lacc);
  atomicAdd(&Sw[b], sacc);
}

// ---- k_chain: 128 blocks x 256 threads; block -> b0 = 16*bid.
// LDS cell (q, b) at word r*RS + b*8 + q*2 holds g[t=win*32+r][b0+b][4q..4q+3]
// as 2 packed-bf16 u32. Producer lane (pb=lane>>2, pq=lane&3) writes its own
// cell per row; consumer lane (grp, cl) reads cell (q=grp, b=cl). Both
// patterns touch all 64 cells/row -> uniform 4 words/bank (b64 width floor).

__device__ __forceinline__ void produce_win(int win, u32* __restrict__ dst,
    const float* __restrict__ hp, int warp){
  #pragma unroll
  for (int k = 0; k < 11; ++k) {
    int r = 3*k + warp;
    if (r < 32) {
      int t = (win << 5) + r;
      f32x4 hv = *(const f32x4*)(hp + (size_t)t*BT);
      float g0 = exp2x(rcpx(1.f + exp2x(hv.x * (-LOG2E))) * LOG2E);
      float g1 = exp2x(rcpx(1.f + exp2x(hv.y * (-LOG2E))) * LOG2E);
      float g2 = exp2x(rcpx(1.f + exp2x(hv.z * (-LOG2E))) * LOG2E);
      float g3 = exp2x(rcpx(1.f + exp2x(hv.w * (-LOG2E))) * LOG2E);
      u32x2 pk; pk.x = cvtpk_bf16(g0, g1); pk.y = cvtpk_bf16(g2, g3);
      *(u32x2*)&dst[r*RS] = pk;
    }
  }
}

__global__ __launch_bounds__(256) void k_chain(const float* __restrict__ h,
    const float* __restrict__ trans, const float* __restrict__ lenw,
    const float* __restrict__ Sw, const int* __restrict__ y0,
    float* __restrict__ out){
  __shared__ __align__(16) u32 gwin[2][32*RS];
  int warp = threadIdx.x >> 6;
  int lane = threadIdx.x & 63;
  int b0   = blockIdx.x << 4;
  int cl   = lane & 15, grp = lane >> 4;

  // producer pointers (lane -> b-slot pb, tag-quad pq)
  int pb = lane >> 2, pq = lane & 3;
  const float* hp = h + (size_t)(b0 + pb)*16 + 4*pq;
  int pcell = pb*8 + pq*2;

  // consumer state
  union { u32 u[2]; s16x4 v; } EApk;   // A = E row cl, k-cols 4grp..+3, *2^-4
  {
    const float* tp = trans + cl*16 + grp*4;
    EApk.u[0] = cvtpk_bf16(exp2x(tp[0]*LOG2E)*0.0625f, exp2x(tp[1]*LOG2E)*0.0625f);
    EApk.u[1] = cvtpk_bf16(exp2x(tp[2]*LOG2E)*0.0625f, exp2x(tp[3]*LOG2E)*0.0625f);
  }
  f32x4 v4 = {0.f, (grp == 0) ? 1.f : 0.f, 0.f, 0.f};  // e_SOS per column
  int   lenc = (int)(lenw[b0 + cl] + 0.5f);
  float lsc  = 0.f;
  const f32x4 z4 = {0.f, 0.f, 0.f, 0.f};
  int ccell = cl*8 + grp*2;

  if (warp < 3) produce_win(0, &gwin[0][pcell], hp, warp);
  __syncthreads();

  for (int win = 0; win < 32; ++win) {
    if (warp < 3) {
      if (win + 1 < 32) produce_win(win + 1, &gwin[(win + 1) & 1][pcell], hp, warp);
    } else {
      const u32* src = &gwin[win & 1][ccell];
      int tbase = win << 5;
      #pragma unroll 4
      for (int r = 0; r < 32; ++r) {
        u32x2 gg = *(const u32x2*)&src[r*RS];
        union { u32 u[2]; s16x4 v; } Bf;
        Bf.u[0] = cvtpk_bf16(v4.x, v4.y);
        Bf.u[1] = cvtpk_bf16(v4.z, v4.w);
        f32x4 dn = mfma16(EApk.v, Bf.v, z4);
        float g0 = __uint_as_float(gg.x << 16);
        float g1 = __uint_as_float(gg.x & 0xffff0000u);
        float g2 = __uint_as_float(gg.y << 16);
        float g3 = __uint_as_float(gg.y & 0xffff0000u);
        bool live = (tbase + r) < lenc;
        v4.x = live ? dn.x*g0 : v4.x;
        v4.y = live ? dn.y*g1 : v4.y;
        v4.z = live ? dn.z*g2 : v4.z;
        v4.w = live ? dn.w*g3 : v4.w;
      }
      // per-column power-of-2 renorm (column = lanes cl, cl+16, cl+32, cl+48)
      float mx = fmaxf(fmaxf(v4.x, v4.y), fmaxf(v4.z, v4.w));
      mx = fmaxf(mx, __shfl_xor(mx, 16));
      mx = fmaxf(mx, __shfl_xor(mx, 32));
      int eb = (int)((__float_as_uint(mx) >> 23) & 0xff) - 127;
      float sc = __uint_as_float((u32)(127 - eb) << 23);
      v4.x *= sc; v4.y *= sc; v4.z *= sc; v4.w *= sc;
      lsc += (float)eb;
    }
    __syncthreads();
  }

  if (warp == 3) {
    // Z = ln( sum_i v[i]*exp(trans[EOS][i]) ) + (lsc + 4*len)*ln2
    const float* te = trans + 32 + grp*4;    // EOS_IDX=2 row
    float p = v4.x*exp2x(te[0]*LOG2E) + v4.y*exp2x(te[1]*LOG2E)
            + v4.z*exp2x(te[2]*LOG2E) + v4.w*exp2x(te[3]*LOG2E);
    p += __shfl_xor(p, 16);
    p += __shfl_xor(p, 32);
    float contrib = 0.f;
    if (grp == 0) {
      float Z = (log2x(p) + lsc + 4.f*(float)lenc) * LN2;
      int lastTag = y0[(size_t)lenc*Bsz + (b0 + cl)];
      float Sb = Sw[b0 + cl] + trans[lastTag];   // trans[PAD=0][lastTag]
      contrib = (Z - Sb) * (1.f/2048.f);
    }
    contrib += __shfl_xor(contrib, 1);
    contrib += __shfl_xor(contrib, 2);
    contrib += __shfl_xor(contrib, 4);
    contrib += __shfl_xor(contrib, 8);
    if (lane == 0) atomicAdd(out, contrib);
  }
}

extern "C" void kernel_launch(void* const* d_in, const int* in_sizes, int n_in,
                              void* d_out, int out_size, void* d_ws, size_t ws_size,
                              hipStream_t stream) {
  const float* h     = (const float*)d_in[0];
  const int*   y0    = (const int*)d_in[1];
  const float* mask  = (const float*)d_in[2];
  const float* trans = (const float*)d_in[3];
  float* out  = (float*)d_out;
  float* lenw = (float*)d_ws;
  float* Sw   = lenw + Bsz;

  k_zero  <<<16,  256, 0, stream>>>(lenw, Sw, out);
  k_score <<<256, 256, 0, stream>>>(y0, mask, trans, lenw, Sw);
  k_chain <<<128, 256, 0, stream>>>(h, trans, lenw, Sw, y0, out);
}